// Round 10
// baseline (1046.588 us; speedup 1.0000x reference)
//
#include <hip/hip_runtime.h>
#include <math.h>

// B=2, C=128, H=192, W=192, NH=4, WS=8, HD=32, N=64, SHIFT=4, HID=512, NWIN=576
#define SCALEf 0.1767766952966369f  // 32^-0.5

typedef short s16x8 __attribute__((ext_vector_type(8)));
typedef float f32x4 __attribute__((ext_vector_type(4)));
typedef unsigned u32x4 __attribute__((ext_vector_type(4)));

__device__ __forceinline__ short f2bf(float f) {
    unsigned u = __float_as_uint(f);
    u += 0x7FFF + ((u >> 16) & 1);
    return (short)(u >> 16);
}
__device__ __forceinline__ float bf2f_lo(unsigned u) { return __uint_as_float(u << 16); }
__device__ __forceinline__ float bf2f_hi(unsigned u) { return __uint_as_float(u & 0xffff0000u); }
__device__ __forceinline__ float gelu_f(float u) {
    float z = 1.5957691216057308f * u * (1.0f + 0.044715f * u * u);
    return u / (1.0f + __expf(-z));
}
__device__ __forceinline__ s16x8 u4_to_s8(unsigned a0, unsigned a1, unsigned a2, unsigned a3) {
    union { u32x4 a; s16x8 b; } c;
    c.a[0] = a0; c.a[1] = a1; c.a[2] = a2; c.a[3] = a3;
    return c.b;
}
__device__ __forceinline__ int region_code(int h, int w) {
    return ((h < 184) ? 0 : (h < 188 ? 3 : 6)) + ((w < 184) ? 0 : (w < 188 ? 1 : 2));
}

// ---------------------------------------------------------------------------
// NCHW -> BHWC transpose. xh kept fp32 (residual use); x/src/tgt also emitted
// as bf16 (GEMM-input copies).
__global__ __launch_bounds__(256) void k_transpose(
    const float* __restrict__ x, const float* __restrict__ s, const float* __restrict__ t,
    float* __restrict__ xo, short* __restrict__ xb, short* __restrict__ sb, short* __restrict__ tb)
{
    int which = blockIdx.z;
    const float* in = which == 0 ? x : (which == 1 ? s : t);
    short* outb = which == 0 ? xb : (which == 1 ? sb : tb);
    __shared__ float tile[32][33];
    int by = blockIdx.y;
    int b = by >> 2;
    int c0 = (by & 3) * 32;
    int p0 = blockIdx.x * 32;
    int tx = threadIdx.x & 31;
    int ty = threadIdx.x >> 5;
    const float* ip = in + (size_t)b * 128 * 36864;
    #pragma unroll
    for (int k = 0; k < 4; ++k) {
        int c = c0 + ty + 8 * k;
        tile[ty + 8 * k][tx] = ip[(size_t)c * 36864 + p0 + tx];
    }
    __syncthreads();
    #pragma unroll
    for (int k = 0; k < 4; ++k) {
        int p = p0 + ty + 8 * k;
        float v = tile[tx][ty + 8 * k];
        size_t off = (size_t)b * 36864 * 128 + (size_t)p * 128 + c0 + tx;
        if (which == 0) xo[off] = v;
        outb[off] = f2bf(v);
    }
}

// ---------------------------------------------------------------------------
// Fold projection: W2 = pW @ mW; write bf16 W2T[n][k] + fp32 b2 = pb @ mW
__global__ __launch_bounds__(256) void k_fold_proj(
    const float* __restrict__ pW, const float* __restrict__ pb,
    const float* __restrict__ mW, short* __restrict__ W2T, float* __restrict__ b2)
{
    if (blockIdx.x < 64) {
        int o = blockIdx.x * 256 + threadIdx.x;
        int i = o >> 7, c = o & 127;
        float acc = 0.f;
        for (int k = 0; k < 128; ++k) acc = fmaf(pW[i * 128 + k], mW[k * 128 + c], acc);
        W2T[c * 128 + i] = f2bf(acc);
    } else {
        int c = threadIdx.x;
        if (c < 128) {
            float acc = 0.f;
            for (int k = 0; k < 128; ++k) acc = fmaf(pb[k], mW[k * 128 + c], acc);
            b2[c] = acc;
        }
    }
}

// ---------------------------------------------------------------------------
// Weight prep (per depth): bf16 [n][k] layouts.
__global__ __launch_bounds__(256) void k_prep(
    const float* __restrict__ f1W, const float* __restrict__ f2W,
    const float* __restrict__ convW, const float* __restrict__ qW,
    const float* __restrict__ kvW,
    short* __restrict__ W1T, short* __restrict__ W2Tm, short* __restrict__ cwb,
    short* __restrict__ qWT, short* __restrict__ kvWT)
{
    int idx = blockIdx.x * 256 + threadIdx.x;
    if (idx < 65536) {
        int n = idx >> 7, k = idx & 127;
        W1T[idx] = f2bf(f1W[k * 512 + n]);
    } else if (idx < 131072) {
        int j = idx - 65536;
        int n = j >> 9, k = j & 511;
        W2Tm[j] = f2bf(f2W[k * 128 + n]);
    } else if (idx < 425984) {
        int j = idx - 131072;
        int ci = j & 255;
        int co = (j >> 8) & 127;
        int k9 = j >> 15;
        cwb[j] = f2bf(convW[(co * 256 + ci) * 9 + k9]);
    } else if (idx < 442368) {
        int j = idx - 425984;
        int n = j >> 7, k = j & 127;
        qWT[j] = f2bf(qW[k * 128 + n]);
    } else if (idx < 475136) {
        int j = idx - 442368;
        int n = j >> 7, k = j & 127;
        kvWT[j] = f2bf(kvW[k * 256 + n]);
    }
}

// ---------------------------------------------------------------------------
// Fused MFMA window attention v7 (round-5 config, best measured).
__global__ __launch_bounds__(256, 3) void k_attn_mfma(
    const float* __restrict__ xh, const short* __restrict__ xbf,
    const short* __restrict__ sbf, const short* __restrict__ tbf,
    const short* __restrict__ qWT, const float* __restrict__ qb,
    const short* __restrict__ kvWT, const float* __restrict__ kvb,
    const float* __restrict__ relb, const short* __restrict__ W2T, const float* __restrict__ b2,
    const float* __restrict__ g1, const float* __restrict__ b1,
    short* __restrict__ sa, short* __restrict__ ta, int shift)
{
    __shared__ short s_q[64 * 136];    // 17408 B
    __shared__ short s_kk[64 * 136];   // 17408 B
    __shared__ short s_vt[128 * 72];   // 18432 B  -> total 53248 B

    int gid = blockIdx.x;
    int branch = gid >= 1152;
    int wid = branch ? gid - 1152 : gid;
    const short* featb = branch ? tbf : sbf;
    short* outb = branch ? ta : sa;
    int b = wid / 576;
    int wi = wid - b * 576;
    int wh = wi / 24, ww = wi - wh * 24;

    int tid = threadIdx.x;
    int h = tid >> 6;
    int lane = tid & 63;
    int ln = lane & 15, quad = lane >> 4;
    int ho = h * 32;
    int koff = quad * 8;

    size_t rowoff[4];
    #pragma unroll
    for (int mt = 0; mt < 4; ++mt) {
        int tok = mt * 16 + ln;
        int ti = tok >> 3, tj = tok & 7;
        int hh = wh * 8 + ti + shift; if (hh >= 192) hh -= 192;
        int wz = ww * 8 + tj + shift; if (wz >= 192) wz -= 192;
        rowoff[mt] = (((size_t)b * 192 + hh) * 192 + wz) * 128;
    }

    // ---- merged Q/K/V projections: one kc loop, 24 MFMA per iteration ----
    {
        f32x4 accq[4][2] = {};
        f32x4 acck[4][2] = {};
        f32x4 accv[2][4] = {};
        #pragma unroll
        for (int kc = 0; kc < 4; ++kc) {
            s16x8 ax[4], af[4];
            #pragma unroll
            for (int mt = 0; mt < 4; ++mt) {
                ax[mt] = *(const s16x8*)(xbf + rowoff[mt] + kc * 32 + koff);
                af[mt] = *(const s16x8*)(featb + rowoff[mt] + kc * 32 + koff);
            }
            s16x8 qw[2], kw[2], vw[2];
            #pragma unroll
            for (int nt = 0; nt < 2; ++nt) {
                qw[nt] = *(const s16x8*)(qWT + (ho + nt * 16 + ln) * 128 + kc * 32 + koff);
                kw[nt] = *(const s16x8*)(kvWT + (ho + nt * 16 + ln) * 128 + kc * 32 + koff);
                vw[nt] = *(const s16x8*)(kvWT + (128 + ho + nt * 16 + ln) * 128 + kc * 32 + koff);
            }
            #pragma unroll
            for (int nt = 0; nt < 2; ++nt)
                #pragma unroll
                for (int mt = 0; mt < 4; ++mt) {
                    accq[mt][nt] = __builtin_amdgcn_mfma_f32_16x16x32_bf16(ax[mt], qw[nt], accq[mt][nt], 0, 0, 0);
                    acck[mt][nt] = __builtin_amdgcn_mfma_f32_16x16x32_bf16(af[mt], kw[nt], acck[mt][nt], 0, 0, 0);
                    accv[nt][mt] = __builtin_amdgcn_mfma_f32_16x16x32_bf16(vw[nt], af[mt], accv[nt][mt], 0, 0, 0);
                }
        }
        #pragma unroll
        for (int nt = 0; nt < 2; ++nt) {
            int col = ho + nt * 16 + ln;
            float bq = qb[col];
            float bk = kvb[col];
            #pragma unroll
            for (int mt = 0; mt < 4; ++mt)
                #pragma unroll
                for (int r = 0; r < 4; ++r) {
                    s_q[(mt * 16 + quad * 4 + r) * 136 + col] = f2bf((accq[mt][nt][r] + bq) * SCALEf);
                    s_kk[(mt * 16 + quad * 4 + r) * 136 + col] = f2bf(acck[mt][nt][r] + bk);
                }
        }
        #pragma unroll
        for (int md = 0; md < 2; ++md)
            #pragma unroll
            for (int r = 0; r < 4; ++r) {
                int d = ho + md * 16 + quad * 4 + r;
                float bb = kvb[128 + d];
                #pragma unroll
                for (int nt = 0; nt < 4; ++nt)
                    s_vt[d * 72 + nt * 16 + ln] = f2bf(accv[md][nt][r] + bb);
            }
    }

    // ---- mask region codes (per-lane, packed) ----
    int cq_code[4];
    int ckp[4];
    if (shift) {
        #pragma unroll
        for (int nq = 0; nq < 4; ++nq) {
            int q = nq * 16 + ln;
            cq_code[nq] = region_code(wh * 8 + (q >> 3), ww * 8 + (q & 7));
        }
        #pragma unroll
        for (int mtk = 0; mtk < 4; ++mtk) {
            int c = 0;
            #pragma unroll
            for (int r = 0; r < 4; ++r) {
                int kt = mtk * 16 + quad * 4 + r;
                c |= region_code(wh * 8 + (kt >> 3), ww * 8 + (kt & 7)) << (8 * r);
            }
            ckp[mtk] = c;
        }
    }

    // ---- swapped QK^T -> in-register softmax -> cross-quad P exchange -> PV ----
    f32x4 acco[4][2] = {};
    #pragma unroll
    for (int nq = 0; nq < 4; ++nq) {
        s16x8 bq = *(const s16x8*)(s_q + (nq * 16 + ln) * 136 + ho + koff);
        f32x4 st[4];
        #pragma unroll
        for (int mtk = 0; mtk < 4; ++mtk) {
            s16x8 aK = *(const s16x8*)(s_kk + (mtk * 16 + ln) * 136 + ho + koff);
            f32x4 z = {};
            st[mtk] = __builtin_amdgcn_mfma_f32_16x16x32_bf16(aK, bq, z, 0, 0, 0);
        }
        int q = nq * 16 + ln;
        int qti = q >> 3, qtj = q & 7;
        float vals[16];
        #pragma unroll
        for (int mtk = 0; mtk < 4; ++mtk)
            #pragma unroll
            for (int r = 0; r < 4; ++r) {
                int kt = mtk * 16 + quad * 4 + r;
                int dr = qti - (kt >> 3) + 7, dc = qtj - (kt & 7) + 7;
                float v = st[mtk][r] + relb[(dr * 15 + dc) * 4 + h];
                if (shift && cq_code[nq] != ((ckp[mtk] >> (8 * r)) & 255)) v -= 100.0f;
                vals[mtk * 4 + r] = v;
            }
        float mx = vals[0];
        #pragma unroll
        for (int i = 1; i < 16; ++i) mx = fmaxf(mx, vals[i]);
        mx = fmaxf(mx, __shfl_xor(mx, 16));
        mx = fmaxf(mx, __shfl_xor(mx, 32));
        float sum = 0.f;
        #pragma unroll
        for (int i = 0; i < 16; ++i) { vals[i] = __expf(vals[i] - mx); sum += vals[i]; }
        sum += __shfl_xor(sum, 16);
        sum += __shfl_xor(sum, 32);
        float inv = 1.0f / sum;
        unsigned pd[4][2];
        #pragma unroll
        for (int mtk = 0; mtk < 4; ++mtk)
            #pragma unroll
            for (int rp = 0; rp < 2; ++rp) {
                unsigned lo16 = (unsigned short)f2bf(vals[mtk * 4 + 2 * rp] * inv);
                unsigned hi16 = (unsigned short)f2bf(vals[mtk * 4 + 2 * rp + 1] * inv);
                pd[mtk][rp] = lo16 | (hi16 << 16);
            }
        #pragma unroll
        for (int kc2 = 0; kc2 < 2; ++kc2) {
            unsigned ad[4];
            #pragma unroll
            for (int rp = 0; rp < 2; ++rp) {
                unsigned X0 = pd[2 * kc2][rp], X1 = pd[2 * kc2 + 1][rp];
                unsigned B0 = __shfl_xor(X0, 16);
                unsigned C0 = __shfl_xor(X0, 32);
                unsigned D0 = __shfl_xor(B0, 32);
                unsigned B1 = __shfl_xor(X1, 16);
                unsigned C1 = __shfl_xor(X1, 32);
                unsigned D1 = __shfl_xor(B1, 32);
                unsigned lo = quad == 0 ? X0 : quad == 1 ? D0 : quad == 2 ? C1 : B1;
                unsigned hi = quad == 0 ? B0 : quad == 1 ? C0 : quad == 2 ? D1 : X1;
                ad[rp] = lo; ad[2 + rp] = hi;
            }
            s16x8 ap = u4_to_s8(ad[0], ad[1], ad[2], ad[3]);
            #pragma unroll
            for (int nt2 = 0; nt2 < 2; ++nt2) {
                s16x8 bv = *(const s16x8*)(s_vt + (ho + nt2 * 16 + ln) * 72 + kc2 * 32 + koff);
                acco[nq][nt2] = __builtin_amdgcn_mfma_f32_16x16x32_bf16(ap, bv, acco[nq][nt2], 0, 0, 0);
            }
        }
    }
    #pragma unroll
    for (int nq = 0; nq < 4; ++nq)
        #pragma unroll
        for (int nt2 = 0; nt2 < 2; ++nt2)
            #pragma unroll
            for (int r = 0; r < 4; ++r)
                s_q[(nq * 16 + quad * 4 + r) * 136 + ho + nt2 * 16 + ln] = f2bf(acco[nq][nt2][r]);
    __syncthreads();

    // ---- folded out-projection + LN + residual (bf16 store) ----
    {
        f32x4 accp[8] = {};
        for (int kc = 0; kc < 4; ++kc) {
            s16x8 a = *(const s16x8*)(s_q + (h * 16 + ln) * 136 + kc * 32 + koff);
            #pragma unroll
            for (int nt = 0; nt < 8; ++nt) {
                s16x8 bfr = *(const s16x8*)(W2T + (nt * 16 + ln) * 128 + kc * 32 + koff);
                accp[nt] = __builtin_amdgcn_mfma_f32_16x16x32_bf16(a, bfr, accp[nt], 0, 0, 0);
            }
        }
        #pragma unroll
        for (int nt = 0; nt < 8; ++nt) {
            float bb = b2[nt * 16 + ln];
            #pragma unroll
            for (int r = 0; r < 4; ++r) accp[nt][r] += bb;
        }
        #pragma unroll
        for (int r = 0; r < 4; ++r) {
            float sm = 0.f, sq = 0.f;
            #pragma unroll
            for (int nt = 0; nt < 8; ++nt) { float v = accp[nt][r]; sm += v; sq = fmaf(v, v, sq); }
            sm += __shfl_xor(sm, 1); sq += __shfl_xor(sq, 1);
            sm += __shfl_xor(sm, 2); sq += __shfl_xor(sq, 2);
            sm += __shfl_xor(sm, 4); sq += __shfl_xor(sq, 4);
            sm += __shfl_xor(sm, 8); sq += __shfl_xor(sq, 8);
            float mean = sm * (1.0f / 128.0f);
            float var = sq * (1.0f / 128.0f) - mean * mean;
            float rstd = rsqrtf(var + 1e-5f);
            int token = h * 16 + quad * 4 + r;
            int ti = token >> 3, tj = token & 7;
            int hh = wh * 8 + ti + shift; if (hh >= 192) hh -= 192;
            int wz = ww * 8 + tj + shift; if (wz >= 192) wz -= 192;
            size_t rb = (((size_t)b * 192 + hh) * 192 + wz) * 128;
            #pragma unroll
            for (int nt = 0; nt < 8; ++nt) {
                int col = nt * 16 + ln;
                float o = xh[rb + col] + fmaf((accp[nt][r] - mean) * rstd, g1[col], b1[col]);
                outb[rb + col] = f2bf(o);
            }
        }
    }
}

// ---------------------------------------------------------------------------
// MFMA MLP v6: LDS-staged chunk weights shared by 8 waves, double-buffered.
// (unchanged)
__global__ __launch_bounds__(512, 4) void k_mlp_mfma(
    const short* __restrict__ sab, const short* __restrict__ tab,
    const short* __restrict__ W1T, const float* __restrict__ f1b,
    const short* __restrict__ W2T, const float* __restrict__ f2b,
    const float* __restrict__ g2, const float* __restrict__ b2n,
    short* __restrict__ catb)
{
    __shared__ short s_w[2 * 9216];   // per buf: W1 4096 shorts + W2 128*40 shorts = 36864 B

    int gid = blockIdx.x;
    int br = gid >= 576;
    int bi = br ? gid - 576 : gid;
    const short* X = br ? tab : sab;

    int tid = threadIdx.x;
    int w = tid >> 6, lane = tid & 63;
    int ln = lane & 15, quad = lane >> 4;
    int koff = quad * 8;
    int tok = bi * 128 + w * 16 + ln;

    int r1 = tid >> 4, s1 = tid & 15;             // W1: 32 rows x 16 segs
    int d1 = r1 * 128 + ((s1 ^ (r1 & 7)) << 3);   // swizzled dest (shorts)
    const short* g1p = W1T + r1 * 128 + s1 * 8;   // + ch*4096
    int r2 = tid >> 2, s2 = tid & 3;              // W2: 128 rows x 4 segs
    int d2 = 4096 + r2 * 40 + s2 * 8;
    const short* g2p = W2T + r2 * 512 + s2 * 8;   // + ch*32

    s16x8 xf[4];
    #pragma unroll
    for (int kc = 0; kc < 4; ++kc)
        xf[kc] = *(const s16x8*)(X + (size_t)tok * 128 + kc * 32 + koff);

    {
        uint4 pw1 = *(const uint4*)(g1p);
        uint4 pw2 = *(const uint4*)(g2p);
        *(uint4*)(s_w + d1) = pw1;
        *(uint4*)(s_w + d2) = pw2;
    }
    __syncthreads();

    f32x4 acc2[8] = {};

    #pragma unroll
    for (int ch = 0; ch < 16; ++ch) {
        const short* wb = s_w + (ch & 1) * 9216;

        uint4 pw1, pw2;
        if (ch < 15) {
            pw1 = *(const uint4*)(g1p + (ch + 1) * 4096);
            pw2 = *(const uint4*)(g2p + (ch + 1) * 32);
        }

        f32x4 acc1[2] = {};
        #pragma unroll
        for (int kc = 0; kc < 4; ++kc) {
            int slot = ((kc * 4 + quad) ^ (ln & 7)) << 3;
            s16x8 aw0 = *(const s16x8*)(wb + ln * 128 + slot);
            s16x8 aw1 = *(const s16x8*)(wb + (16 + ln) * 128 + slot);
            acc1[0] = __builtin_amdgcn_mfma_f32_16x16x32_bf16(aw0, xf[kc], acc1[0], 0, 0, 0);
            acc1[1] = __builtin_amdgcn_mfma_f32_16x16x32_bf16(aw1, xf[kc], acc1[1], 0, 0, 0);
        }
        float4 fb0 = *(const float4*)(f1b + ch * 32 + quad * 4);
        float4 fb1 = *(const float4*)(f1b + ch * 32 + 16 + quad * 4);
        unsigned pd0[2], pd1[2];
        {
            float h0 = gelu_f(acc1[0][0] + fb0.x);
            float h1 = gelu_f(acc1[0][1] + fb0.y);
            float h2 = gelu_f(acc1[0][2] + fb0.z);
            float h3 = gelu_f(acc1[0][3] + fb0.w);
            pd0[0] = (unsigned short)f2bf(h0) | ((unsigned)(unsigned short)f2bf(h1) << 16);
            pd0[1] = (unsigned short)f2bf(h2) | ((unsigned)(unsigned short)f2bf(h3) << 16);
            float g0 = gelu_f(acc1[1][0] + fb1.x);
            float g1v = gelu_f(acc1[1][1] + fb1.y);
            float g2v = gelu_f(acc1[1][2] + fb1.z);
            float g3 = gelu_f(acc1[1][3] + fb1.w);
            pd1[0] = (unsigned short)f2bf(g0) | ((unsigned)(unsigned short)f2bf(g1v) << 16);
            pd1[1] = (unsigned short)f2bf(g2v) | ((unsigned)(unsigned short)f2bf(g3) << 16);
        }
        unsigned ad[4];
        #pragma unroll
        for (int rp = 0; rp < 2; ++rp) {
            unsigned X0 = pd0[rp], X1 = pd1[rp];
            unsigned B0 = __shfl_xor(X0, 16);
            unsigned C0 = __shfl_xor(X0, 32);
            unsigned D0 = __shfl_xor(B0, 32);
            unsigned B1 = __shfl_xor(X1, 16);
            unsigned C1 = __shfl_xor(X1, 32);
            unsigned D1 = __shfl_xor(B1, 32);
            unsigned lo = quad == 0 ? X0 : quad == 1 ? D0 : quad == 2 ? C1 : B1;
            unsigned hi = quad == 0 ? B0 : quad == 1 ? C0 : quad == 2 ? D1 : X1;
            ad[rp] = lo; ad[2 + rp] = hi;
        }
        s16x8 bh = u4_to_s8(ad[0], ad[1], ad[2], ad[3]);
        #pragma unroll
        for (int nt = 0; nt < 8; ++nt) {
            s16x8 aw2 = *(const s16x8*)(wb + 4096 + (nt * 16 + ln) * 40 + koff);
            acc2[nt] = __builtin_amdgcn_mfma_f32_16x16x32_bf16(aw2, bh, acc2[nt], 0, 0, 0);
        }

        if (ch < 15) {
            __syncthreads();
            short* nb = s_w + ((ch + 1) & 1) * 9216;
            *(uint4*)(nb + d1) = pw1;
            *(uint4*)(nb + d2) = pw2;
            __syncthreads();
        }
    }

    {
        float sm = 0.f, sq = 0.f;
        #pragma unroll
        for (int nt = 0; nt < 8; ++nt) {
            float4 fb2 = *(const float4*)(f2b + nt * 16 + quad * 4);
            acc2[nt][0] += fb2.x; acc2[nt][1] += fb2.y;
            acc2[nt][2] += fb2.z; acc2[nt][3] += fb2.w;
            #pragma unroll
            for (int r = 0; r < 4; ++r) {
                float v = acc2[nt][r];
                sm += v; sq = fmaf(v, v, sq);
            }
        }
        sm += __shfl_xor(sm, 16); sq += __shfl_xor(sq, 16);
        sm += __shfl_xor(sm, 32); sq += __shfl_xor(sq, 32);
        float mean = sm * (1.0f / 128.0f);
        float var = sq * (1.0f / 128.0f) - mean * mean;
        float rstd = rsqrtf(var + 1e-5f);
        #pragma unroll
        for (int nt = 0; nt < 8; ++nt) {
            int c0 = nt * 16 + quad * 4;
            uint2 xr2 = *(const uint2*)(X + (size_t)tok * 128 + c0);
            float4 gg = *(const float4*)(g2 + c0);
            float4 bb = *(const float4*)(b2n + c0);
            float x0 = bf2f_lo(xr2.x), x1 = bf2f_hi(xr2.x);
            float x2 = bf2f_lo(xr2.y), x3 = bf2f_hi(xr2.y);
            unsigned short o0 = (unsigned short)f2bf(x0 + fmaf((acc2[nt][0] - mean) * rstd, gg.x, bb.x));
            unsigned short o1 = (unsigned short)f2bf(x1 + fmaf((acc2[nt][1] - mean) * rstd, gg.y, bb.y));
            unsigned short o2 = (unsigned short)f2bf(x2 + fmaf((acc2[nt][2] - mean) * rstd, gg.z, bb.z));
            unsigned short o3 = (unsigned short)f2bf(x3 + fmaf((acc2[nt][3] - mean) * rstd, gg.w, bb.w));
            uint2 st;
            st.x = (unsigned)o0 | ((unsigned)o1 << 16);
            st.y = (unsigned)o2 | ((unsigned)o3 << 16);
            *(uint2*)(catb + (size_t)tok * 256 + br * 128 + c0) = st;
        }
    }
}

// ---------------------------------------------------------------------------
// MFMA implicit-GEMM conv3x3 v2: tile 2 rows x 16 cols (was 2x32).
// Patch 4x18x256 bf16 in LDS = 38016 B -> 4 blocks/CU (was 71808 B -> 2).
// Same MFMA-per-output; grid 2304. Wave w: 32 couts x 32 positions.
__global__ __launch_bounds__(256) void k_conv_mfma(
    const short* __restrict__ catb, const short* __restrict__ cwb,
    const float* __restrict__ bias, const float* __restrict__ pa,
    float* __restrict__ out, short* __restrict__ obf, int nchw)
{
    __shared__ short s_in[72 * 264];   // 38016 B; aliased as fp32 s_out [128][33] in NCHW epilogue
    int gid = blockIdx.x;
    int b = gid / 1152;
    int r0 = gid - b * 1152;
    int hp = r0 / 12;
    int wt = r0 - hp * 12;
    int h0 = hp * 2, w0 = wt * 16;
    int tid = threadIdx.x;

    // stage 4 x 18 x 256 bf16 patch (rows h0-1..h0+2, cols w0-1..w0+16)
    for (int idx = tid; idx < 2304; idx += 256) {
        int row = idx >> 5, seg = idx & 31;
        int dh = row / 18, c18 = row - dh * 18;
        int hh = h0 - 1 + dh;
        int wc = w0 - 1 + c18;
        uint4 v = make_uint4(0u, 0u, 0u, 0u);
        if (hh >= 0 && hh < 192 && wc >= 0 && wc < 192)
            v = *(const uint4*)(catb + (((size_t)b * 192 + hh) * 192 + wc) * 256 + seg * 8);
        *(uint4*)(&s_in[row * 264 + seg * 8]) = v;
    }
    __syncthreads();

    int w = tid >> 6, lane = tid & 63;
    int ln = lane & 15, quad = lane >> 4;
    f32x4 acc[2][2] = {};

    #pragma unroll
    for (int kh = 0; kh < 3; ++kh) {
        #pragma unroll
        for (int kw = 0; kw < 3; ++kw) {
            const short* wbase = cwb + (size_t)((kh * 3 + kw) * 128 + w * 32) * 256;
            const short* ab[2];
            #pragma unroll
            for (int mt = 0; mt < 2; ++mt) {
                int prow = (mt + kh) * 18 + ln + kw;
                ab[mt] = s_in + prow * 264 + quad * 8;
            }
            for (int kc = 0; kc < 8; ++kc) {
                s16x8 bfr[2];
                #pragma unroll
                for (int nt = 0; nt < 2; ++nt)
                    bfr[nt] = *(const s16x8*)(wbase + (nt * 16 + ln) * 256 + kc * 32 + quad * 8);
                s16x8 afr[2];
                #pragma unroll
                for (int mt = 0; mt < 2; ++mt)
                    afr[mt] = *(const s16x8*)(ab[mt] + kc * 32);
                #pragma unroll
                for (int nt = 0; nt < 2; ++nt)
                    #pragma unroll
                    for (int mt = 0; mt < 2; ++mt)
                        acc[mt][nt] = __builtin_amdgcn_mfma_f32_16x16x32_bf16(afr[mt], bfr[nt], acc[mt][nt], 0, 0, 0);
            }
        }
    }

    if (!nchw) {
        #pragma unroll
        for (int nt = 0; nt < 2; ++nt) {
            int co = w * 32 + nt * 16 + ln;
            float bs = bias[co], pv = pa[co];
            #pragma unroll
            for (int mt = 0; mt < 2; ++mt) {
                #pragma unroll
                for (int r = 0; r < 4; ++r) {
                    int pw = quad * 4 + r;
                    float v = acc[mt][nt][r] + bs;
                    v = (v >= 0.f) ? v : pv * v;
                    size_t off = (((size_t)b * 192 + h0 + mt) * 192 + w0 + pw) * 128 + co;
                    out[off] = v;
                    obf[off] = f2bf(v);
                }
            }
        }
    } else {
        __syncthreads();                 // all s_in reads done before alias overwrite
        float* s_out = (float*)s_in;     // [128][33]
        #pragma unroll
        for (int nt = 0; nt < 2; ++nt) {
            int co = w * 32 + nt * 16 + ln;
            float bs = bias[co], pv = pa[co];
            #pragma unroll
            for (int mt = 0; mt < 2; ++mt) {
                int pos0 = mt * 16 + quad * 4;
                #pragma unroll
                for (int r = 0; r < 4; ++r) {
                    float v = acc[mt][nt][r] + bs;
                    v = (v >= 0.f) ? v : pv * v;
                    s_out[co * 33 + pos0 + r] = v;
                }
            }
        }
        __syncthreads();
        for (int idx = tid; idx < 1024; idx += 256) {
            int co = idx >> 3;
            int pr = (idx >> 2) & 1;
            int sg = idx & 3;
            const float* sp = s_out + co * 33 + pr * 16 + sg * 4;
            float4 v = make_float4(sp[0], sp[1], sp[2], sp[3]);
            *(float4*)(out + (((size_t)b * 128 + co) * 192 + h0 + pr) * 192 + w0 + sg * 4) = v;
        }
    }
}

// ---------------------------------------------------------------------------
extern "C" void kernel_launch(void* const* d_in, const int* in_sizes, int n_in,
                              void* d_out, int out_size, void* d_ws, size_t ws_size,
                              hipStream_t stream)
{
    const float* x    = (const float*)d_in[0];
    const float* src  = (const float*)d_in[1];
    const float* tgt  = (const float*)d_in[2];
    const float* qW   = (const float*)d_in[3];
    const float* qb   = (const float*)d_in[4];
    const float* kvW  = (const float*)d_in[5];
    const float* kvb  = (const float*)d_in[6];
    const float* pW   = (const float*)d_in[7];
    const float* pb   = (const float*)d_in[8];
    const float* relb = (const float*)d_in[9];
    const float* mW   = (const float*)d_in[10];
    const float* n1g  = (const float*)d_in[11];
    const float* n1b  = (const float*)d_in[12];
    const float* f1W  = (const float*)d_in[13];
    const float* f1b  = (const float*)d_in[14];
    const float* f2W  = (const float*)d_in[15];
    const float* f2b  = (const float*)d_in[16];
    const float* n2g  = (const float*)d_in[17];
    const float* n2b  = (const float*)d_in[18];
    const float* convW= (const float*)d_in[19];
    const float* convb= (const float*)d_in[20];
    const float* pa   = (const float*)d_in[21];
    float* out = (float*)d_out;

    const size_t FR = (size_t)2 * 192 * 192 * 128;
    float* ws   = (float*)d_ws;
    float* xh   = ws;                       // FR floats
    float* b2   = ws + FR;                  // 128 floats
    short* W1T  = (short*)(b2 + 128);
    short* W2Tm = W1T + 65536;
    short* cwb  = W2Tm + 65536;
    short* qWT  = cwb + 294912;
    short* kvWT = qWT + 16384;
    short* W2Tp = kvWT + 32768;
    short* xbf  = W2Tp + 16384;             // FR shorts
    short* sbf  = xbf + FR;                 // FR shorts
    short* tbf  = sbf + FR;                 // FR shorts
    short* sbb  = tbf + FR;                 // FR shorts (attn out, source branch)
    short* tbb  = sbb + FR;                 // FR shorts (attn out, target branch)
    short* catb = tbb + FR;                 // 2*FR shorts

    k_transpose<<<dim3(1152, 8, 3), 256, 0, stream>>>(x, src, tgt, xh, xbf, sbf, tbf);

    for (int d = 0; d < 2; ++d) {
        int shift = d ? 4 : 0;
        k_fold_proj<<<65, 256, 0, stream>>>(pW + d * 16384, pb + d * 128, mW + d * 16384, W2Tp, b2);
        k_prep<<<1856, 256, 0, stream>>>(f1W + d * 65536, f2W + d * 65536,
                                         convW + d * 294912, qW + d * 16384, kvW + d * 32768,
                                         W1T, W2Tm, cwb, qWT, kvWT);
        k_attn_mfma<<<2304, 256, 0, stream>>>(xh, xbf, sbf, tbf,
            qWT, qb + d * 128, kvWT, kvb + d * 256,
            relb + d * 900, W2Tp, b2, n1g + d * 128, n1b + d * 128, sbb, tbb, shift);
        k_mlp_mfma<<<1152, 512, 0, stream>>>(sbb, tbb, W1T, f1b + d * 512,
            W2Tm, f2b + d * 128, n2g + d * 128, n2b + d * 128, catb);
        k_conv_mfma<<<2304, 256, 0, stream>>>(catb, cwb, convb + d * 128, pa + d * 128,
            d == 1 ? out : xh, xbf, d == 1 ? 1 : 0);
    }
}

// Round 11
// 959.074 us; speedup vs baseline: 1.0912x; 1.0912x over previous
//
#include <hip/hip_runtime.h>
#include <math.h>

// B=2, C=128, H=192, W=192, NH=4, WS=8, HD=32, N=64, SHIFT=4, HID=512, NWIN=576
#define SCALEf 0.1767766952966369f  // 32^-0.5

typedef short s16x8 __attribute__((ext_vector_type(8)));
typedef float f32x4 __attribute__((ext_vector_type(4)));
typedef unsigned u32x4 __attribute__((ext_vector_type(4)));

__device__ __forceinline__ short f2bf(float f) {
    unsigned u = __float_as_uint(f);
    u += 0x7FFF + ((u >> 16) & 1);
    return (short)(u >> 16);
}
__device__ __forceinline__ float bf2f_lo(unsigned u) { return __uint_as_float(u << 16); }
__device__ __forceinline__ float bf2f_hi(unsigned u) { return __uint_as_float(u & 0xffff0000u); }
__device__ __forceinline__ float gelu_f(float u) {
    float z = 1.5957691216057308f * u * (1.0f + 0.044715f * u * u);
    return u / (1.0f + __expf(-z));
}
__device__ __forceinline__ s16x8 u4_to_s8(unsigned a0, unsigned a1, unsigned a2, unsigned a3) {
    union { u32x4 a; s16x8 b; } c;
    c.a[0] = a0; c.a[1] = a1; c.a[2] = a2; c.a[3] = a3;
    return c.b;
}
__device__ __forceinline__ int region_code(int h, int w) {
    return ((h < 184) ? 0 : (h < 188 ? 3 : 6)) + ((w < 184) ? 0 : (w < 188 ? 1 : 2));
}

// ---------------------------------------------------------------------------
// NCHW -> BHWC transpose. xh kept fp32 (residual use); x/src/tgt also emitted
// as bf16 (GEMM-input copies).
__global__ __launch_bounds__(256) void k_transpose(
    const float* __restrict__ x, const float* __restrict__ s, const float* __restrict__ t,
    float* __restrict__ xo, short* __restrict__ xb, short* __restrict__ sb, short* __restrict__ tb)
{
    int which = blockIdx.z;
    const float* in = which == 0 ? x : (which == 1 ? s : t);
    short* outb = which == 0 ? xb : (which == 1 ? sb : tb);
    __shared__ float tile[32][33];
    int by = blockIdx.y;
    int b = by >> 2;
    int c0 = (by & 3) * 32;
    int p0 = blockIdx.x * 32;
    int tx = threadIdx.x & 31;
    int ty = threadIdx.x >> 5;
    const float* ip = in + (size_t)b * 128 * 36864;
    #pragma unroll
    for (int k = 0; k < 4; ++k) {
        int c = c0 + ty + 8 * k;
        tile[ty + 8 * k][tx] = ip[(size_t)c * 36864 + p0 + tx];
    }
    __syncthreads();
    #pragma unroll
    for (int k = 0; k < 4; ++k) {
        int p = p0 + ty + 8 * k;
        float v = tile[tx][ty + 8 * k];
        size_t off = (size_t)b * 36864 * 128 + (size_t)p * 128 + c0 + tx;
        if (which == 0) xo[off] = v;
        outb[off] = f2bf(v);
    }
}

// ---------------------------------------------------------------------------
// Fold projection: W2 = pW @ mW; write bf16 W2T[n][k] + fp32 b2 = pb @ mW
__global__ __launch_bounds__(256) void k_fold_proj(
    const float* __restrict__ pW, const float* __restrict__ pb,
    const float* __restrict__ mW, short* __restrict__ W2T, float* __restrict__ b2)
{
    if (blockIdx.x < 64) {
        int o = blockIdx.x * 256 + threadIdx.x;
        int i = o >> 7, c = o & 127;
        float acc = 0.f;
        for (int k = 0; k < 128; ++k) acc = fmaf(pW[i * 128 + k], mW[k * 128 + c], acc);
        W2T[c * 128 + i] = f2bf(acc);
    } else {
        int c = threadIdx.x;
        if (c < 128) {
            float acc = 0.f;
            for (int k = 0; k < 128; ++k) acc = fmaf(pb[k], mW[k * 128 + c], acc);
            b2[c] = acc;
        }
    }
}

// ---------------------------------------------------------------------------
// Weight prep (per depth): bf16 [n][k] layouts.
__global__ __launch_bounds__(256) void k_prep(
    const float* __restrict__ f1W, const float* __restrict__ f2W,
    const float* __restrict__ convW, const float* __restrict__ qW,
    const float* __restrict__ kvW,
    short* __restrict__ W1T, short* __restrict__ W2Tm, short* __restrict__ cwb,
    short* __restrict__ qWT, short* __restrict__ kvWT)
{
    int idx = blockIdx.x * 256 + threadIdx.x;
    if (idx < 65536) {
        int n = idx >> 7, k = idx & 127;
        W1T[idx] = f2bf(f1W[k * 512 + n]);
    } else if (idx < 131072) {
        int j = idx - 65536;
        int n = j >> 9, k = j & 511;
        W2Tm[j] = f2bf(f2W[k * 128 + n]);
    } else if (idx < 425984) {
        int j = idx - 131072;
        int ci = j & 255;
        int co = (j >> 8) & 127;
        int k9 = j >> 15;
        cwb[j] = f2bf(convW[(co * 256 + ci) * 9 + k9]);
    } else if (idx < 442368) {
        int j = idx - 425984;
        int n = j >> 7, k = j & 127;
        qWT[j] = f2bf(qW[k * 128 + n]);
    } else if (idx < 475136) {
        int j = idx - 442368;
        int n = j >> 7, k = j & 127;
        kvWT[j] = f2bf(kvW[k * 256 + n]);
    }
}

// ---------------------------------------------------------------------------
// Fused MFMA window attention v7 (round-5 config, best measured).
__global__ __launch_bounds__(256, 3) void k_attn_mfma(
    const float* __restrict__ xh, const short* __restrict__ xbf,
    const short* __restrict__ sbf, const short* __restrict__ tbf,
    const short* __restrict__ qWT, const float* __restrict__ qb,
    const short* __restrict__ kvWT, const float* __restrict__ kvb,
    const float* __restrict__ relb, const short* __restrict__ W2T, const float* __restrict__ b2,
    const float* __restrict__ g1, const float* __restrict__ b1,
    short* __restrict__ sa, short* __restrict__ ta, int shift)
{
    __shared__ short s_q[64 * 136];    // 17408 B
    __shared__ short s_kk[64 * 136];   // 17408 B
    __shared__ short s_vt[128 * 72];   // 18432 B  -> total 53248 B

    int gid = blockIdx.x;
    int branch = gid >= 1152;
    int wid = branch ? gid - 1152 : gid;
    const short* featb = branch ? tbf : sbf;
    short* outb = branch ? ta : sa;
    int b = wid / 576;
    int wi = wid - b * 576;
    int wh = wi / 24, ww = wi - wh * 24;

    int tid = threadIdx.x;
    int h = tid >> 6;
    int lane = tid & 63;
    int ln = lane & 15, quad = lane >> 4;
    int ho = h * 32;
    int koff = quad * 8;

    size_t rowoff[4];
    #pragma unroll
    for (int mt = 0; mt < 4; ++mt) {
        int tok = mt * 16 + ln;
        int ti = tok >> 3, tj = tok & 7;
        int hh = wh * 8 + ti + shift; if (hh >= 192) hh -= 192;
        int wz = ww * 8 + tj + shift; if (wz >= 192) wz -= 192;
        rowoff[mt] = (((size_t)b * 192 + hh) * 192 + wz) * 128;
    }

    // ---- merged Q/K/V projections: one kc loop, 24 MFMA per iteration ----
    {
        f32x4 accq[4][2] = {};
        f32x4 acck[4][2] = {};
        f32x4 accv[2][4] = {};
        #pragma unroll
        for (int kc = 0; kc < 4; ++kc) {
            s16x8 ax[4], af[4];
            #pragma unroll
            for (int mt = 0; mt < 4; ++mt) {
                ax[mt] = *(const s16x8*)(xbf + rowoff[mt] + kc * 32 + koff);
                af[mt] = *(const s16x8*)(featb + rowoff[mt] + kc * 32 + koff);
            }
            s16x8 qw[2], kw[2], vw[2];
            #pragma unroll
            for (int nt = 0; nt < 2; ++nt) {
                qw[nt] = *(const s16x8*)(qWT + (ho + nt * 16 + ln) * 128 + kc * 32 + koff);
                kw[nt] = *(const s16x8*)(kvWT + (ho + nt * 16 + ln) * 128 + kc * 32 + koff);
                vw[nt] = *(const s16x8*)(kvWT + (128 + ho + nt * 16 + ln) * 128 + kc * 32 + koff);
            }
            #pragma unroll
            for (int nt = 0; nt < 2; ++nt)
                #pragma unroll
                for (int mt = 0; mt < 4; ++mt) {
                    accq[mt][nt] = __builtin_amdgcn_mfma_f32_16x16x32_bf16(ax[mt], qw[nt], accq[mt][nt], 0, 0, 0);
                    acck[mt][nt] = __builtin_amdgcn_mfma_f32_16x16x32_bf16(af[mt], kw[nt], acck[mt][nt], 0, 0, 0);
                    accv[nt][mt] = __builtin_amdgcn_mfma_f32_16x16x32_bf16(vw[nt], af[mt], accv[nt][mt], 0, 0, 0);
                }
        }
        #pragma unroll
        for (int nt = 0; nt < 2; ++nt) {
            int col = ho + nt * 16 + ln;
            float bq = qb[col];
            float bk = kvb[col];
            #pragma unroll
            for (int mt = 0; mt < 4; ++mt)
                #pragma unroll
                for (int r = 0; r < 4; ++r) {
                    s_q[(mt * 16 + quad * 4 + r) * 136 + col] = f2bf((accq[mt][nt][r] + bq) * SCALEf);
                    s_kk[(mt * 16 + quad * 4 + r) * 136 + col] = f2bf(acck[mt][nt][r] + bk);
                }
        }
        #pragma unroll
        for (int md = 0; md < 2; ++md)
            #pragma unroll
            for (int r = 0; r < 4; ++r) {
                int d = ho + md * 16 + quad * 4 + r;
                float bb = kvb[128 + d];
                #pragma unroll
                for (int nt = 0; nt < 4; ++nt)
                    s_vt[d * 72 + nt * 16 + ln] = f2bf(accv[md][nt][r] + bb);
            }
    }

    // ---- mask region codes (per-lane, packed) ----
    int cq_code[4];
    int ckp[4];
    if (shift) {
        #pragma unroll
        for (int nq = 0; nq < 4; ++nq) {
            int q = nq * 16 + ln;
            cq_code[nq] = region_code(wh * 8 + (q >> 3), ww * 8 + (q & 7));
        }
        #pragma unroll
        for (int mtk = 0; mtk < 4; ++mtk) {
            int c = 0;
            #pragma unroll
            for (int r = 0; r < 4; ++r) {
                int kt = mtk * 16 + quad * 4 + r;
                c |= region_code(wh * 8 + (kt >> 3), ww * 8 + (kt & 7)) << (8 * r);
            }
            ckp[mtk] = c;
        }
    }

    // ---- swapped QK^T -> in-register softmax -> cross-quad P exchange -> PV ----
    f32x4 acco[4][2] = {};
    #pragma unroll
    for (int nq = 0; nq < 4; ++nq) {
        s16x8 bq = *(const s16x8*)(s_q + (nq * 16 + ln) * 136 + ho + koff);
        f32x4 st[4];
        #pragma unroll
        for (int mtk = 0; mtk < 4; ++mtk) {
            s16x8 aK = *(const s16x8*)(s_kk + (mtk * 16 + ln) * 136 + ho + koff);
            f32x4 z = {};
            st[mtk] = __builtin_amdgcn_mfma_f32_16x16x32_bf16(aK, bq, z, 0, 0, 0);
        }
        int q = nq * 16 + ln;
        int qti = q >> 3, qtj = q & 7;
        float vals[16];
        #pragma unroll
        for (int mtk = 0; mtk < 4; ++mtk)
            #pragma unroll
            for (int r = 0; r < 4; ++r) {
                int kt = mtk * 16 + quad * 4 + r;
                int dr = qti - (kt >> 3) + 7, dc = qtj - (kt & 7) + 7;
                float v = st[mtk][r] + relb[(dr * 15 + dc) * 4 + h];
                if (shift && cq_code[nq] != ((ckp[mtk] >> (8 * r)) & 255)) v -= 100.0f;
                vals[mtk * 4 + r] = v;
            }
        float mx = vals[0];
        #pragma unroll
        for (int i = 1; i < 16; ++i) mx = fmaxf(mx, vals[i]);
        mx = fmaxf(mx, __shfl_xor(mx, 16));
        mx = fmaxf(mx, __shfl_xor(mx, 32));
        float sum = 0.f;
        #pragma unroll
        for (int i = 0; i < 16; ++i) { vals[i] = __expf(vals[i] - mx); sum += vals[i]; }
        sum += __shfl_xor(sum, 16);
        sum += __shfl_xor(sum, 32);
        float inv = 1.0f / sum;
        unsigned pd[4][2];
        #pragma unroll
        for (int mtk = 0; mtk < 4; ++mtk)
            #pragma unroll
            for (int rp = 0; rp < 2; ++rp) {
                unsigned lo16 = (unsigned short)f2bf(vals[mtk * 4 + 2 * rp] * inv);
                unsigned hi16 = (unsigned short)f2bf(vals[mtk * 4 + 2 * rp + 1] * inv);
                pd[mtk][rp] = lo16 | (hi16 << 16);
            }
        #pragma unroll
        for (int kc2 = 0; kc2 < 2; ++kc2) {
            unsigned ad[4];
            #pragma unroll
            for (int rp = 0; rp < 2; ++rp) {
                unsigned X0 = pd[2 * kc2][rp], X1 = pd[2 * kc2 + 1][rp];
                unsigned B0 = __shfl_xor(X0, 16);
                unsigned C0 = __shfl_xor(X0, 32);
                unsigned D0 = __shfl_xor(B0, 32);
                unsigned B1 = __shfl_xor(X1, 16);
                unsigned C1 = __shfl_xor(X1, 32);
                unsigned D1 = __shfl_xor(B1, 32);
                unsigned lo = quad == 0 ? X0 : quad == 1 ? D0 : quad == 2 ? C1 : B1;
                unsigned hi = quad == 0 ? B0 : quad == 1 ? C0 : quad == 2 ? D1 : X1;
                ad[rp] = lo; ad[2 + rp] = hi;
            }
            s16x8 ap = u4_to_s8(ad[0], ad[1], ad[2], ad[3]);
            #pragma unroll
            for (int nt2 = 0; nt2 < 2; ++nt2) {
                s16x8 bv = *(const s16x8*)(s_vt + (ho + nt2 * 16 + ln) * 72 + kc2 * 32 + koff);
                acco[nq][nt2] = __builtin_amdgcn_mfma_f32_16x16x32_bf16(ap, bv, acco[nq][nt2], 0, 0, 0);
            }
        }
    }
    #pragma unroll
    for (int nq = 0; nq < 4; ++nq)
        #pragma unroll
        for (int nt2 = 0; nt2 < 2; ++nt2)
            #pragma unroll
            for (int r = 0; r < 4; ++r)
                s_q[(nq * 16 + quad * 4 + r) * 136 + ho + nt2 * 16 + ln] = f2bf(acco[nq][nt2][r]);
    __syncthreads();

    // ---- folded out-projection + LN + residual (bf16 store) ----
    {
        f32x4 accp[8] = {};
        for (int kc = 0; kc < 4; ++kc) {
            s16x8 a = *(const s16x8*)(s_q + (h * 16 + ln) * 136 + kc * 32 + koff);
            #pragma unroll
            for (int nt = 0; nt < 8; ++nt) {
                s16x8 bfr = *(const s16x8*)(W2T + (nt * 16 + ln) * 128 + kc * 32 + koff);
                accp[nt] = __builtin_amdgcn_mfma_f32_16x16x32_bf16(a, bfr, accp[nt], 0, 0, 0);
            }
        }
        #pragma unroll
        for (int nt = 0; nt < 8; ++nt) {
            float bb = b2[nt * 16 + ln];
            #pragma unroll
            for (int r = 0; r < 4; ++r) accp[nt][r] += bb;
        }
        #pragma unroll
        for (int r = 0; r < 4; ++r) {
            float sm = 0.f, sq = 0.f;
            #pragma unroll
            for (int nt = 0; nt < 8; ++nt) { float v = accp[nt][r]; sm += v; sq = fmaf(v, v, sq); }
            sm += __shfl_xor(sm, 1); sq += __shfl_xor(sq, 1);
            sm += __shfl_xor(sm, 2); sq += __shfl_xor(sq, 2);
            sm += __shfl_xor(sm, 4); sq += __shfl_xor(sq, 4);
            sm += __shfl_xor(sm, 8); sq += __shfl_xor(sq, 8);
            float mean = sm * (1.0f / 128.0f);
            float var = sq * (1.0f / 128.0f) - mean * mean;
            float rstd = rsqrtf(var + 1e-5f);
            int token = h * 16 + quad * 4 + r;
            int ti = token >> 3, tj = token & 7;
            int hh = wh * 8 + ti + shift; if (hh >= 192) hh -= 192;
            int wz = ww * 8 + tj + shift; if (wz >= 192) wz -= 192;
            size_t rb = (((size_t)b * 192 + hh) * 192 + wz) * 128;
            #pragma unroll
            for (int nt = 0; nt < 8; ++nt) {
                int col = nt * 16 + ln;
                float o = xh[rb + col] + fmaf((accp[nt][r] - mean) * rstd, g1[col], b1[col]);
                outb[rb + col] = f2bf(o);
            }
        }
    }
}

// ---------------------------------------------------------------------------
// MFMA MLP v6: LDS-staged chunk weights shared by 8 waves, double-buffered.
// (unchanged)
__global__ __launch_bounds__(512, 4) void k_mlp_mfma(
    const short* __restrict__ sab, const short* __restrict__ tab,
    const short* __restrict__ W1T, const float* __restrict__ f1b,
    const short* __restrict__ W2T, const float* __restrict__ f2b,
    const float* __restrict__ g2, const float* __restrict__ b2n,
    short* __restrict__ catb)
{
    __shared__ short s_w[2 * 9216];   // per buf: W1 4096 shorts + W2 128*40 shorts = 36864 B

    int gid = blockIdx.x;
    int br = gid >= 576;
    int bi = br ? gid - 576 : gid;
    const short* X = br ? tab : sab;

    int tid = threadIdx.x;
    int w = tid >> 6, lane = tid & 63;
    int ln = lane & 15, quad = lane >> 4;
    int koff = quad * 8;
    int tok = bi * 128 + w * 16 + ln;

    int r1 = tid >> 4, s1 = tid & 15;             // W1: 32 rows x 16 segs
    int d1 = r1 * 128 + ((s1 ^ (r1 & 7)) << 3);   // swizzled dest (shorts)
    const short* g1p = W1T + r1 * 128 + s1 * 8;   // + ch*4096
    int r2 = tid >> 2, s2 = tid & 3;              // W2: 128 rows x 4 segs
    int d2 = 4096 + r2 * 40 + s2 * 8;
    const short* g2p = W2T + r2 * 512 + s2 * 8;   // + ch*32

    s16x8 xf[4];
    #pragma unroll
    for (int kc = 0; kc < 4; ++kc)
        xf[kc] = *(const s16x8*)(X + (size_t)tok * 128 + kc * 32 + koff);

    {
        uint4 pw1 = *(const uint4*)(g1p);
        uint4 pw2 = *(const uint4*)(g2p);
        *(uint4*)(s_w + d1) = pw1;
        *(uint4*)(s_w + d2) = pw2;
    }
    __syncthreads();

    f32x4 acc2[8] = {};

    #pragma unroll
    for (int ch = 0; ch < 16; ++ch) {
        const short* wb = s_w + (ch & 1) * 9216;

        uint4 pw1, pw2;
        if (ch < 15) {
            pw1 = *(const uint4*)(g1p + (ch + 1) * 4096);
            pw2 = *(const uint4*)(g2p + (ch + 1) * 32);
        }

        f32x4 acc1[2] = {};
        #pragma unroll
        for (int kc = 0; kc < 4; ++kc) {
            int slot = ((kc * 4 + quad) ^ (ln & 7)) << 3;
            s16x8 aw0 = *(const s16x8*)(wb + ln * 128 + slot);
            s16x8 aw1 = *(const s16x8*)(wb + (16 + ln) * 128 + slot);
            acc1[0] = __builtin_amdgcn_mfma_f32_16x16x32_bf16(aw0, xf[kc], acc1[0], 0, 0, 0);
            acc1[1] = __builtin_amdgcn_mfma_f32_16x16x32_bf16(aw1, xf[kc], acc1[1], 0, 0, 0);
        }
        float4 fb0 = *(const float4*)(f1b + ch * 32 + quad * 4);
        float4 fb1 = *(const float4*)(f1b + ch * 32 + 16 + quad * 4);
        unsigned pd0[2], pd1[2];
        {
            float h0 = gelu_f(acc1[0][0] + fb0.x);
            float h1 = gelu_f(acc1[0][1] + fb0.y);
            float h2 = gelu_f(acc1[0][2] + fb0.z);
            float h3 = gelu_f(acc1[0][3] + fb0.w);
            pd0[0] = (unsigned short)f2bf(h0) | ((unsigned)(unsigned short)f2bf(h1) << 16);
            pd0[1] = (unsigned short)f2bf(h2) | ((unsigned)(unsigned short)f2bf(h3) << 16);
            float g0 = gelu_f(acc1[1][0] + fb1.x);
            float g1v = gelu_f(acc1[1][1] + fb1.y);
            float g2v = gelu_f(acc1[1][2] + fb1.z);
            float g3 = gelu_f(acc1[1][3] + fb1.w);
            pd1[0] = (unsigned short)f2bf(g0) | ((unsigned)(unsigned short)f2bf(g1v) << 16);
            pd1[1] = (unsigned short)f2bf(g2v) | ((unsigned)(unsigned short)f2bf(g3) << 16);
        }
        unsigned ad[4];
        #pragma unroll
        for (int rp = 0; rp < 2; ++rp) {
            unsigned X0 = pd0[rp], X1 = pd1[rp];
            unsigned B0 = __shfl_xor(X0, 16);
            unsigned C0 = __shfl_xor(X0, 32);
            unsigned D0 = __shfl_xor(B0, 32);
            unsigned B1 = __shfl_xor(X1, 16);
            unsigned C1 = __shfl_xor(X1, 32);
            unsigned D1 = __shfl_xor(B1, 32);
            unsigned lo = quad == 0 ? X0 : quad == 1 ? D0 : quad == 2 ? C1 : B1;
            unsigned hi = quad == 0 ? B0 : quad == 1 ? C0 : quad == 2 ? D1 : X1;
            ad[rp] = lo; ad[2 + rp] = hi;
        }
        s16x8 bh = u4_to_s8(ad[0], ad[1], ad[2], ad[3]);
        #pragma unroll
        for (int nt = 0; nt < 8; ++nt) {
            s16x8 aw2 = *(const s16x8*)(wb + 4096 + (nt * 16 + ln) * 40 + koff);
            acc2[nt] = __builtin_amdgcn_mfma_f32_16x16x32_bf16(aw2, bh, acc2[nt], 0, 0, 0);
        }

        if (ch < 15) {
            __syncthreads();
            short* nb = s_w + ((ch + 1) & 1) * 9216;
            *(uint4*)(nb + d1) = pw1;
            *(uint4*)(nb + d2) = pw2;
            __syncthreads();
        }
    }

    {
        float sm = 0.f, sq = 0.f;
        #pragma unroll
        for (int nt = 0; nt < 8; ++nt) {
            float4 fb2 = *(const float4*)(f2b + nt * 16 + quad * 4);
            acc2[nt][0] += fb2.x; acc2[nt][1] += fb2.y;
            acc2[nt][2] += fb2.z; acc2[nt][3] += fb2.w;
            #pragma unroll
            for (int r = 0; r < 4; ++r) {
                float v = acc2[nt][r];
                sm += v; sq = fmaf(v, v, sq);
            }
        }
        sm += __shfl_xor(sm, 16); sq += __shfl_xor(sq, 16);
        sm += __shfl_xor(sm, 32); sq += __shfl_xor(sq, 32);
        float mean = sm * (1.0f / 128.0f);
        float var = sq * (1.0f / 128.0f) - mean * mean;
        float rstd = rsqrtf(var + 1e-5f);
        #pragma unroll
        for (int nt = 0; nt < 8; ++nt) {
            int c0 = nt * 16 + quad * 4;
            uint2 xr2 = *(const uint2*)(X + (size_t)tok * 128 + c0);
            float4 gg = *(const float4*)(g2 + c0);
            float4 bb = *(const float4*)(b2n + c0);
            float x0 = bf2f_lo(xr2.x), x1 = bf2f_hi(xr2.x);
            float x2 = bf2f_lo(xr2.y), x3 = bf2f_hi(xr2.y);
            unsigned short o0 = (unsigned short)f2bf(x0 + fmaf((acc2[nt][0] - mean) * rstd, gg.x, bb.x));
            unsigned short o1 = (unsigned short)f2bf(x1 + fmaf((acc2[nt][1] - mean) * rstd, gg.y, bb.y));
            unsigned short o2 = (unsigned short)f2bf(x2 + fmaf((acc2[nt][2] - mean) * rstd, gg.z, bb.z));
            unsigned short o3 = (unsigned short)f2bf(x3 + fmaf((acc2[nt][3] - mean) * rstd, gg.w, bb.w));
            uint2 st;
            st.x = (unsigned)o0 | ((unsigned)o1 << 16);
            st.y = (unsigned)o2 | ((unsigned)o3 << 16);
            *(uint2*)(catb + (size_t)tok * 256 + br * 128 + c0) = st;
        }
    }
}

// ---------------------------------------------------------------------------
// MFMA implicit-GEMM conv3x3 v3: v1 tile (2 rows x 32 cols, grid 1152) with
// ci split into two staged halves. LDS = 136 pos x 136 (128 ci + 8 pad)
// shorts = 36992 B -> 4 blocks/CU (v1: 71808 -> 2) at UNCHANGED per-block
// weight traffic (v2's regression was doubled weight streaming).
__global__ __launch_bounds__(256) void k_conv_mfma(
    const short* __restrict__ catb, const short* __restrict__ cwb,
    const float* __restrict__ bias, const float* __restrict__ pa,
    float* __restrict__ out, short* __restrict__ obf, int nchw)
{
    __shared__ short s_in[136 * 136];   // 36992 B; aliased as fp32 s_out [128][65] in NCHW epilogue
    int gid = blockIdx.x;
    int b = gid / 576;
    int r0 = gid - b * 576;
    int hp = r0 / 6;
    int wt = r0 - hp * 6;
    int h0 = hp * 2, w0 = wt * 32;
    int tid = threadIdx.x;
    int w = tid >> 6, lane = tid & 63;
    int ln = lane & 15, quad = lane >> 4;

    f32x4 acc[4][2] = {};

    for (int half = 0; half < 2; ++half) {
        if (half) __syncthreads();   // all reads of half-0 done before overwrite
        // stage 4 x 34 positions x 128 ci of this half
        for (int idx = tid; idx < 2176; idx += 256) {
            int row = idx >> 4, seg = idx & 15;
            int dh = row / 34, wc34 = row - dh * 34;
            int hh = h0 - 1 + dh;
            int wc = w0 - 1 + wc34;
            uint4 v = make_uint4(0u, 0u, 0u, 0u);
            if (hh >= 0 && hh < 192 && wc >= 0 && wc < 192)
                v = *(const uint4*)(catb + (((size_t)b * 192 + hh) * 192 + wc) * 256 + half * 128 + seg * 8);
            *(uint4*)(&s_in[row * 136 + seg * 8]) = v;
        }
        __syncthreads();

        #pragma unroll
        for (int kh = 0; kh < 3; ++kh) {
            #pragma unroll
            for (int kw = 0; kw < 3; ++kw) {
                const short* wbase = cwb + (size_t)((kh * 3 + kw) * 128 + w * 32) * 256 + half * 128;
                const short* ab[4];
                #pragma unroll
                for (int mt = 0; mt < 4; ++mt) {
                    int prow = ((mt >> 1) + kh) * 34 + (mt & 1) * 16 + ln + kw;
                    ab[mt] = s_in + prow * 136 + quad * 8;
                }
                for (int kc = 0; kc < 4; ++kc) {
                    s16x8 bfr[2];
                    #pragma unroll
                    for (int nt = 0; nt < 2; ++nt)
                        bfr[nt] = *(const s16x8*)(wbase + (nt * 16 + ln) * 256 + kc * 32 + quad * 8);
                    s16x8 afr[4];
                    #pragma unroll
                    for (int mt = 0; mt < 4; ++mt)
                        afr[mt] = *(const s16x8*)(ab[mt] + kc * 32);
                    #pragma unroll
                    for (int nt = 0; nt < 2; ++nt)
                        #pragma unroll
                        for (int mt = 0; mt < 4; ++mt)
                            acc[mt][nt] = __builtin_amdgcn_mfma_f32_16x16x32_bf16(afr[mt], bfr[nt], acc[mt][nt], 0, 0, 0);
                }
            }
        }
    }

    if (!nchw) {
        #pragma unroll
        for (int nt = 0; nt < 2; ++nt) {
            int co = w * 32 + nt * 16 + ln;
            float bs = bias[co], pv = pa[co];
            #pragma unroll
            for (int mt = 0; mt < 4; ++mt) {
                int pr = mt >> 1;
                #pragma unroll
                for (int r = 0; r < 4; ++r) {
                    int pw = (mt & 1) * 16 + quad * 4 + r;
                    float v = acc[mt][nt][r] + bs;
                    v = (v >= 0.f) ? v : pv * v;
                    size_t off = (((size_t)b * 192 + h0 + pr) * 192 + w0 + pw) * 128 + co;
                    out[off] = v;
                    obf[off] = f2bf(v);
                }
            }
        }
    } else {
        __syncthreads();                 // all s_in reads done before alias overwrite
        float* s_out = (float*)s_in;     // [128][65] = 33280 B <= 36992 B
        #pragma unroll
        for (int nt = 0; nt < 2; ++nt) {
            int co = w * 32 + nt * 16 + ln;
            float bs = bias[co], pv = pa[co];
            #pragma unroll
            for (int mt = 0; mt < 4; ++mt) {
                int pos0 = (mt >> 1) * 32 + (mt & 1) * 16 + quad * 4;
                #pragma unroll
                for (int r = 0; r < 4; ++r) {
                    float v = acc[mt][nt][r] + bs;
                    v = (v >= 0.f) ? v : pv * v;
                    s_out[co * 65 + pos0 + r] = v;
                }
            }
        }
        __syncthreads();
        for (int idx = tid; idx < 2048; idx += 256) {
            int co = idx >> 4;
            int pr = (idx >> 3) & 1;
            int sg = idx & 7;
            const float* sp = s_out + co * 65 + pr * 32 + sg * 4;
            float4 v = make_float4(sp[0], sp[1], sp[2], sp[3]);
            *(float4*)(out + (((size_t)b * 128 + co) * 192 + h0 + pr) * 192 + w0 + sg * 4) = v;
        }
    }
}

// ---------------------------------------------------------------------------
extern "C" void kernel_launch(void* const* d_in, const int* in_sizes, int n_in,
                              void* d_out, int out_size, void* d_ws, size_t ws_size,
                              hipStream_t stream)
{
    const float* x    = (const float*)d_in[0];
    const float* src  = (const float*)d_in[1];
    const float* tgt  = (const float*)d_in[2];
    const float* qW   = (const float*)d_in[3];
    const float* qb   = (const float*)d_in[4];
    const float* kvW  = (const float*)d_in[5];
    const float* kvb  = (const float*)d_in[6];
    const float* pW   = (const float*)d_in[7];
    const float* pb   = (const float*)d_in[8];
    const float* relb = (const float*)d_in[9];
    const float* mW   = (const float*)d_in[10];
    const float* n1g  = (const float*)d_in[11];
    const float* n1b  = (const float*)d_in[12];
    const float* f1W  = (const float*)d_in[13];
    const float* f1b  = (const float*)d_in[14];
    const float* f2W  = (const float*)d_in[15];
    const float* f2b  = (const float*)d_in[16];
    const float* n2g  = (const float*)d_in[17];
    const float* n2b  = (const float*)d_in[18];
    const float* convW= (const float*)d_in[19];
    const float* convb= (const float*)d_in[20];
    const float* pa   = (const float*)d_in[21];
    float* out = (float*)d_out;

    const size_t FR = (size_t)2 * 192 * 192 * 128;
    float* ws   = (float*)d_ws;
    float* xh   = ws;                       // FR floats
    float* b2   = ws + FR;                  // 128 floats
    short* W1T  = (short*)(b2 + 128);
    short* W2Tm = W1T + 65536;
    short* cwb  = W2Tm + 65536;
    short* qWT  = cwb + 294912;
    short* kvWT = qWT + 16384;
    short* W2Tp = kvWT + 32768;
    short* xbf  = W2Tp + 16384;             // FR shorts
    short* sbf  = xbf + FR;                 // FR shorts
    short* tbf  = sbf + FR;                 // FR shorts
    short* sbb  = tbf + FR;                 // FR shorts (attn out, source branch)
    short* tbb  = sbb + FR;                 // FR shorts (attn out, target branch)
    short* catb = tbb + FR;                 // 2*FR shorts

    k_transpose<<<dim3(1152, 8, 3), 256, 0, stream>>>(x, src, tgt, xh, xbf, sbf, tbf);

    for (int d = 0; d < 2; ++d) {
        int shift = d ? 4 : 0;
        k_fold_proj<<<65, 256, 0, stream>>>(pW + d * 16384, pb + d * 128, mW + d * 16384, W2Tp, b2);
        k_prep<<<1856, 256, 0, stream>>>(f1W + d * 65536, f2W + d * 65536,
                                         convW + d * 294912, qW + d * 16384, kvW + d * 32768,
                                         W1T, W2Tm, cwb, qWT, kvWT);
        k_attn_mfma<<<2304, 256, 0, stream>>>(xh, xbf, sbf, tbf,
            qWT, qb + d * 128, kvWT, kvb + d * 256,
            relb + d * 900, W2Tp, b2, n1g + d * 128, n1b + d * 128, sbb, tbb, shift);
        k_mlp_mfma<<<1152, 512, 0, stream>>>(sbb, tbb, W1T, f1b + d * 512,
            W2Tm, f2b + d * 128, n2g + d * 128, n2b + d * 128, catb);
        k_conv_mfma<<<1152, 256, 0, stream>>>(catb, cwb, convb + d * 128, pa + d * 128,
            d == 1 ? out : xh, xbf, d == 1 ? 1 : 0);
    }
}